// Round 1
// baseline (1975.641 us; speedup 1.0000x reference)
//
#include <hip/hip_runtime.h>

#define H 64
#define GDIM 256   // 4H gate rows
#define TT 512     // sequence length
#define BB 512     // batch

__device__ __forceinline__ float sigm(float x) { return 1.f / (1.f + __expf(-x)); }
__device__ __forceinline__ float tanh_fast(float x) { return 1.f - 2.f / (__expf(2.f * x) + 1.f); }

// Layer 0: input size 4. One block per (batch, direction). 256 threads, thread r owns gate row r.
__global__ __launch_bounds__(256) void lstm_l0(
    const float* __restrict__ x,       // [B,T,4]
    const float* __restrict__ Wih_f, const float* __restrict__ Whh_f, const float* __restrict__ b_f,
    const float* __restrict__ Wih_b, const float* __restrict__ Whh_b, const float* __restrict__ b_b,
    float* __restrict__ out0)          // [B,T,128] concat(fwd, bwd)
{
    const int bid = blockIdx.x;
    const int b   = bid >> 1;
    const int dir = bid & 1;
    const int r   = threadIdx.x;

    const float* Wih  = dir ? Wih_b : Wih_f;
    const float* Whh  = dir ? Whh_b : Whh_f;
    const float* bias = dir ? b_b   : b_f;

    // per-thread weights in registers
    float4 wv = ((const float4*)Wih)[r];      // W_ih row r (4 floats)
    float whh[H];
#pragma unroll
    for (int j = 0; j < 16; ++j) {
        float4 v = ((const float4*)(Whh + r * H))[j];
        whh[4*j+0] = v.x; whh[4*j+1] = v.y; whh[4*j+2] = v.z; whh[4*j+3] = v.w;
    }
    const float bv = bias[r];

    __shared__ __align__(16) float h_sh[H];
    __shared__ __align__(16) float gate_sh[GDIM];
    float c = 0.f;
    if (r < H) h_sh[r] = 0.f;
    __syncthreads();

    const float4* x4 = (const float4*)x;   // [B*T] float4
    for (int s = 0; s < TT; ++s) {
        const int t = dir ? (TT - 1 - s) : s;
        float4 xt = x4[b * TT + t];
        float g = bv + wv.x * xt.x + wv.y * xt.y + wv.z * xt.z + wv.w * xt.w;
        const float4* h4 = (const float4*)h_sh;
#pragma unroll
        for (int j = 0; j < 16; ++j) {
            float4 hv = h4[j];
            g += whh[4*j+0] * hv.x + whh[4*j+1] * hv.y + whh[4*j+2] * hv.z + whh[4*j+3] * hv.w;
        }
        // wave-uniform activation: rows [0,128) and [192,256) sigmoid, [128,192) tanh
        float a = (r < 128 || r >= 192) ? sigm(g) : tanh_fast(g);
        gate_sh[r] = a;
        __syncthreads();
        if (r < H) {
            float iv = gate_sh[r], fv = gate_sh[H + r], gv = gate_sh[2*H + r], ov = gate_sh[3*H + r];
            c = fv * c + iv * gv;
            float hv = ov * tanh_fast(c);
            h_sh[r] = hv;
            out0[(size_t)(b * TT + t) * 128 + dir * H + r] = hv;
        }
        __syncthreads();
    }
}

// Layer 1: input size 128. One block per (batch, direction). Accumulates sum over T of h.
__global__ __launch_bounds__(256) void lstm_l1(
    const float* __restrict__ in,      // [B,T,128]
    const float* __restrict__ Wih_f, const float* __restrict__ Whh_f, const float* __restrict__ b_f,
    const float* __restrict__ Wih_b, const float* __restrict__ Whh_b, const float* __restrict__ b_b,
    float* __restrict__ pooled)        // [B,128] sums over T (fwd half | bwd half)
{
    const int bid = blockIdx.x;
    const int b   = bid >> 1;
    const int dir = bid & 1;
    const int r   = threadIdx.x;

    const float* Wih  = dir ? Wih_b : Wih_f;
    const float* Whh  = dir ? Whh_b : Whh_f;
    const float* bias = dir ? b_b   : b_f;

    float wih[128];
#pragma unroll
    for (int j = 0; j < 32; ++j) {
        float4 v = ((const float4*)(Wih + r * 128))[j];
        wih[4*j+0] = v.x; wih[4*j+1] = v.y; wih[4*j+2] = v.z; wih[4*j+3] = v.w;
    }
    float whh[H];
#pragma unroll
    for (int j = 0; j < 16; ++j) {
        float4 v = ((const float4*)(Whh + r * H))[j];
        whh[4*j+0] = v.x; whh[4*j+1] = v.y; whh[4*j+2] = v.z; whh[4*j+3] = v.w;
    }
    const float bv = bias[r];

    __shared__ __align__(16) float x_sh[128];
    __shared__ __align__(16) float h_sh[H];
    __shared__ __align__(16) float gate_sh[GDIM];
    float c = 0.f, hsum = 0.f;
    if (r < H) h_sh[r] = 0.f;
    __syncthreads();

    const float4* in4 = (const float4*)in;
    for (int s = 0; s < TT; ++s) {
        const int t = dir ? (TT - 1 - s) : s;
        if (r < 32) ((float4*)x_sh)[r] = in4[(size_t)(b * TT + t) * 32 + r];
        __syncthreads();   // x_sh staged; h_sh from previous step visible
        float g = bv;
        const float4* x4 = (const float4*)x_sh;
#pragma unroll
        for (int j = 0; j < 32; ++j) {
            float4 xv = x4[j];
            g += wih[4*j+0] * xv.x + wih[4*j+1] * xv.y + wih[4*j+2] * xv.z + wih[4*j+3] * xv.w;
        }
        const float4* h4 = (const float4*)h_sh;
#pragma unroll
        for (int j = 0; j < 16; ++j) {
            float4 hv = h4[j];
            g += whh[4*j+0] * hv.x + whh[4*j+1] * hv.y + whh[4*j+2] * hv.z + whh[4*j+3] * hv.w;
        }
        float a = (r < 128 || r >= 192) ? sigm(g) : tanh_fast(g);
        gate_sh[r] = a;
        __syncthreads();
        if (r < H) {
            float iv = gate_sh[r], fv = gate_sh[H + r], gv = gate_sh[2*H + r], ov = gate_sh[3*H + r];
            c = fv * c + iv * gv;
            float hv = ov * tanh_fast(c);
            h_sh[r] = hv;
            hsum += hv;
        }
        // next iteration's first __syncthreads() makes h_sh/x_sh ordering safe
    }
    if (r < H) pooled[b * 128 + dir * H + r] = hsum;
}

// Final: out[b] = dot(pooled[b], fc_w) / T + fc_b
__global__ __launch_bounds__(64) void fc_head(
    const float* __restrict__ pooled,  // [B,128]
    const float* __restrict__ fcw,     // [128]
    const float* __restrict__ fcb,     // [1]
    float* __restrict__ out)           // [B]
{
    const int b = blockIdx.x;
    const int l = threadIdx.x;         // 64 threads = 1 wave
    float v = pooled[b * 128 + l] * fcw[l] + pooled[b * 128 + 64 + l] * fcw[64 + l];
#pragma unroll
    for (int o = 32; o > 0; o >>= 1) v += __shfl_down(v, o);
    if (l == 0) out[b] = v * (1.f / (float)TT) + fcb[0];
}

extern "C" void kernel_launch(void* const* d_in, const int* in_sizes, int n_in,
                              void* d_out, int out_size, void* d_ws, size_t ws_size,
                              hipStream_t stream) {
    const float* x       = (const float*)d_in[0];
    const float* Wih_l0f = (const float*)d_in[1];
    const float* Whh_l0f = (const float*)d_in[2];
    const float* b_l0f   = (const float*)d_in[3];
    const float* Wih_l0b = (const float*)d_in[4];
    const float* Whh_l0b = (const float*)d_in[5];
    const float* b_l0b   = (const float*)d_in[6];
    const float* Wih_l1f = (const float*)d_in[7];
    const float* Whh_l1f = (const float*)d_in[8];
    const float* b_l1f   = (const float*)d_in[9];
    const float* Wih_l1b = (const float*)d_in[10];
    const float* Whh_l1b = (const float*)d_in[11];
    const float* b_l1b   = (const float*)d_in[12];
    const float* fcw     = (const float*)d_in[13];
    const float* fcb     = (const float*)d_in[14];

    float* out0   = (float*)d_ws;                                    // [B,T,128] = 128 MiB
    float* pooled = (float*)((char*)d_ws + (size_t)BB * TT * 128 * 4); // [B,128]

    lstm_l0<<<BB * 2, 256, 0, stream>>>(x, Wih_l0f, Whh_l0f, b_l0f, Wih_l0b, Whh_l0b, b_l0b, out0);
    lstm_l1<<<BB * 2, 256, 0, stream>>>(out0, Wih_l1f, Whh_l1f, b_l1f, Wih_l1b, Whh_l1b, b_l1b, pooled);
    fc_head<<<BB, 64, 0, stream>>>(pooled, fcw, fcb, (float*)d_out);
}

// Round 2
// 1722.812 us; speedup vs baseline: 1.1468x; 1.1468x over previous
//
#include <hip/hip_runtime.h>
#include <hip/hip_fp16.h>

#define H  64
#define TT 512
#define BB 512

typedef _Float16 half8 __attribute__((ext_vector_type(8)));
typedef float    f32x4 __attribute__((ext_vector_type(4)));
typedef short    s16x4 __attribute__((ext_vector_type(4)));

__device__ __forceinline__ float sigm(float x) { return 1.f / (1.f + __expf(-x)); }
__device__ __forceinline__ float tanh_fast(float x) { return 1.f - 2.f / (__expf(2.f * x) + 1.f); }

// ---------------------------------------------------------------------------
// Prep: convert layer-1 Wih to fp16, permuted so output col = unit*4 + gate.
// out[dir][unit*4+gate][k] = (half) Wih_dir[gate*64+unit][k]
// ---------------------------------------------------------------------------
__global__ __launch_bounds__(256) void prep_w(const float* __restrict__ wf,
                                              const float* __restrict__ wb,
                                              __half* __restrict__ out) {
    int i = blockIdx.x * 256 + threadIdx.x;      // 0 .. 65535
    int dir  = i >> 15;
    int rem  = i & 32767;
    int rowp = rem >> 7;                          // permuted row 0..255
    int k    = rem & 127;
    int unit = rowp >> 2;
    int gate = rowp & 3;
    const float* src = dir ? wb : wf;
    out[i] = __float2half(src[(gate * 64 + unit) * 128 + k]);
}

// ---------------------------------------------------------------------------
// Layer 0: one 64-thread wave per (batch, dir). Thread r owns unit r (all 4
// gates). No gate exchange; only h is broadcast through LDS (16 b128/step).
// Writes h as fp16 into out0 [B*T, 128] (cols 0-63 fwd, 64-127 bwd).
// ---------------------------------------------------------------------------
__global__ __launch_bounds__(64, 1) void lstm_l0(
    const float* __restrict__ x,
    const float* __restrict__ WihF, const float* __restrict__ WhhF, const float* __restrict__ bF,
    const float* __restrict__ WihB, const float* __restrict__ WhhB, const float* __restrict__ bB,
    __half* __restrict__ out0)
{
    const int bid = blockIdx.x;
    const int b   = bid >> 1;
    const int dir = bid & 1;
    const int r   = threadIdx.x;

    const float* Wih  = dir ? WihB : WihF;
    const float* Whh  = dir ? WhhB : WhhF;
    const float* bias = dir ? bB   : bF;

    float4 wx[4];
    float  bv[4];
    float  wh[4][H];
#pragma unroll
    for (int g = 0; g < 4; ++g) {
        wx[g] = ((const float4*)Wih)[g * 64 + r];
        bv[g] = bias[g * 64 + r];
#pragma unroll
        for (int j = 0; j < 16; ++j) {
            float4 v = ((const float4*)(Whh + (g * 64 + r) * H))[j];
            wh[g][4*j+0] = v.x; wh[g][4*j+1] = v.y; wh[g][4*j+2] = v.z; wh[g][4*j+3] = v.w;
        }
    }

    __shared__ __align__(16) float h_sh[H];
    float c = 0.f;
    h_sh[r] = 0.f;
    __syncthreads();

    const float4* x4 = (const float4*)x + (size_t)b * TT;
    const int dt = dir ? -1 : 1;
    int t = dir ? (TT - 1) : 0;
    float4 xt = x4[t];

    for (int s = 0; s < TT; ++s) {
        float4 xnext = x4[(s + 1 < TT) ? (t + dt) : t];

        float gi = bv[0] + wx[0].x*xt.x + wx[0].y*xt.y + wx[0].z*xt.z + wx[0].w*xt.w;
        float gf = bv[1] + wx[1].x*xt.x + wx[1].y*xt.y + wx[1].z*xt.z + wx[1].w*xt.w;
        float gg = bv[2] + wx[2].x*xt.x + wx[2].y*xt.y + wx[2].z*xt.z + wx[2].w*xt.w;
        float go = bv[3] + wx[3].x*xt.x + wx[3].y*xt.y + wx[3].z*xt.z + wx[3].w*xt.w;

        const float4* h4 = (const float4*)h_sh;
#pragma unroll
        for (int j = 0; j < 16; ++j) {
            float4 hv = h4[j];
            gi += wh[0][4*j+0]*hv.x + wh[0][4*j+1]*hv.y + wh[0][4*j+2]*hv.z + wh[0][4*j+3]*hv.w;
            gf += wh[1][4*j+0]*hv.x + wh[1][4*j+1]*hv.y + wh[1][4*j+2]*hv.z + wh[1][4*j+3]*hv.w;
            gg += wh[2][4*j+0]*hv.x + wh[2][4*j+1]*hv.y + wh[2][4*j+2]*hv.z + wh[2][4*j+3]*hv.w;
            go += wh[3][4*j+0]*hv.x + wh[3][4*j+1]*hv.y + wh[3][4*j+2]*hv.z + wh[3][4*j+3]*hv.w;
        }
        float iv = sigm(gi), fv = sigm(gf), gv = tanh_fast(gg), ov = sigm(go);
        c = fv * c + iv * gv;
        float h = ov * tanh_fast(c);

        out0[(size_t)(b * TT + t) * 128 + dir * 64 + r] = __float2half(h);

        __syncthreads();
        h_sh[r] = h;
        __syncthreads();
        xt = xnext;
        t += dt;
    }
}

// ---------------------------------------------------------------------------
// xp GEMM: xp[dir][m][n] = sum_k A[m'][k] * Wb[dir][n][k]   (fp16 in, fp32 acc,
// fp16 out). m is chunk-local (stage s, chunk length Tc); m' maps through the
// per-direction time order. Block = 256 thr = 4 waves; block tile 64m x 256n;
// each wave 16m x 256n (16 MFMA tiles, K=128 -> 64 MFMAs).
// ---------------------------------------------------------------------------
__global__ __launch_bounds__(256) void xp_gemm(
    const __half* __restrict__ A,      // [B*T, 128]
    const __half* __restrict__ Wb,     // [2][256][128] permuted fp16
    __half* __restrict__ xpF, __half* __restrict__ xpB,
    int s, int Tc, int tcShift)
{
    const int dir  = blockIdx.y;
    const int mb   = blockIdx.x;
    const int w    = threadIdx.x >> 6;
    const int lane = threadIdx.x & 63;
    const int quad = lane >> 4;
    const int l16  = lane & 15;

    const int mbase = mb * 64 + w * 16;
    const int m     = mbase + l16;                 // chunk-local row for A-frag
    const int bb    = m >> tcShift;
    const int u     = m & (Tc - 1);
    const int t     = dir ? (TT - 1 - s * Tc - u) : (s * Tc + u);

    const __half* arow = A + (size_t)(bb * TT + t) * 128;
    const __half* wdir = Wb + (size_t)dir * 256 * 128;

    f32x4 acc[16];
#pragma unroll
    for (int nt = 0; nt < 16; ++nt) acc[nt] = (f32x4){0.f, 0.f, 0.f, 0.f};

#pragma unroll
    for (int kk = 0; kk < 4; ++kk) {
        half8 a = *(const half8*)(arow + kk * 32 + quad * 8);
#pragma unroll
        for (int nt = 0; nt < 16; ++nt) {
            half8 bf = *(const half8*)(wdir + (size_t)(nt * 16 + l16) * 128 + kk * 32 + quad * 8);
            acc[nt] = __builtin_amdgcn_mfma_f32_16x16x32_f16(a, bf, acc[nt], 0, 0, 0);
        }
    }

    // Epilogue: stage 16x256 fp16 tile per wave in LDS, then contiguous stores.
    __shared__ __align__(16) __half c_sh[4][16][264];   // pad 264 to break bank collisions
#pragma unroll
    for (int nt = 0; nt < 16; ++nt)
#pragma unroll
        for (int i = 0; i < 4; ++i)
            c_sh[w][quad * 4 + i][nt * 16 + l16] = __float2half(acc[nt][i]);
    __syncthreads();

    __half* dst = (dir ? xpB : xpF) + (size_t)mbase * 256;
#pragma unroll
    for (int rd = 0; rd < 8; ++rd) {
        int ci  = rd * 64 + lane;           // 0..511 chunks of 16B
        int row = ci >> 5;                  // 16 rows
        int off = ci & 31;                  // 32 x 16B per row (512B of data)
        float4 v = *(const float4*)((const char*)&c_sh[w][row][0] + off * 16);
        *(float4*)((char*)dst + (size_t)row * 512 + off * 16) = v;
    }
}

// ---------------------------------------------------------------------------
// Layer 1 recurrent (stage): one 64-thread wave per (batch, dir). Thread r
// owns unit r. Reads precomputed xp (fp16, gate-interleaved: col = r*4+gate)
// with 1-step prefetch. Carries h/c/hsum across stages via state in ws.
// ---------------------------------------------------------------------------
__global__ __launch_bounds__(64, 1) void lstm_l1_rec(
    const __half* __restrict__ xpF, const __half* __restrict__ xpB,
    const float* __restrict__ WhhF, const float* __restrict__ bF,
    const float* __restrict__ WhhB, const float* __restrict__ bB,
    float* __restrict__ state,        // [3][1024][64] : h, c, hsum
    int Tc, int first)
{
    const int bid = blockIdx.x;
    const int b   = bid >> 1;
    const int dir = bid & 1;
    const int r   = threadIdx.x;

    const float* Whh  = dir ? WhhB : WhhF;
    const float* bias = dir ? bB   : bF;

    float bv[4];
    float wh[4][H];
#pragma unroll
    for (int g = 0; g < 4; ++g) {
        bv[g] = bias[g * 64 + r];
#pragma unroll
        for (int j = 0; j < 16; ++j) {
            float4 v = ((const float4*)(Whh + (g * 64 + r) * H))[j];
            wh[g][4*j+0] = v.x; wh[g][4*j+1] = v.y; wh[g][4*j+2] = v.z; wh[g][4*j+3] = v.w;
        }
    }

    float* st_h = state;
    float* st_c = state + 1024 * 64;
    float* st_s = state + 2 * 1024 * 64;

    float h, c, hsum;
    if (first) { h = 0.f; c = 0.f; hsum = 0.f; }
    else { h = st_h[bid * 64 + r]; c = st_c[bid * 64 + r]; hsum = st_s[bid * 64 + r]; }

    __shared__ __align__(16) float h_sh[H];
    h_sh[r] = h;
    __syncthreads();

    const __half* xp = (dir ? xpB : xpF) + (size_t)b * Tc * 256 + r * 4;
    s16x4 xv = *(const s16x4*)xp;

    for (int u = 0; u < Tc; ++u) {
        int un = (u + 1 < Tc) ? (u + 1) : u;
        s16x4 xnext = *(const s16x4*)(xp + (size_t)un * 256);

        union { s16x4 v; __half hh[4]; } ux; ux.v = xv;
        float gi = bv[0] + __half2float(ux.hh[0]);
        float gf = bv[1] + __half2float(ux.hh[1]);
        float gg = bv[2] + __half2float(ux.hh[2]);
        float go = bv[3] + __half2float(ux.hh[3]);

        const float4* h4 = (const float4*)h_sh;
#pragma unroll
        for (int j = 0; j < 16; ++j) {
            float4 hv = h4[j];
            gi += wh[0][4*j+0]*hv.x + wh[0][4*j+1]*hv.y + wh[0][4*j+2]*hv.z + wh[0][4*j+3]*hv.w;
            gf += wh[1][4*j+0]*hv.x + wh[1][4*j+1]*hv.y + wh[1][4*j+2]*hv.z + wh[1][4*j+3]*hv.w;
            gg += wh[2][4*j+0]*hv.x + wh[2][4*j+1]*hv.y + wh[2][4*j+2]*hv.z + wh[2][4*j+3]*hv.w;
            go += wh[3][4*j+0]*hv.x + wh[3][4*j+1]*hv.y + wh[3][4*j+2]*hv.z + wh[3][4*j+3]*hv.w;
        }
        float iv = sigm(gi), fv = sigm(gf), gv = tanh_fast(gg), ov = sigm(go);
        c = fv * c + iv * gv;
        h = ov * tanh_fast(c);
        hsum += h;

        __syncthreads();
        h_sh[r] = h;
        __syncthreads();
        xv = xnext;
    }

    st_h[bid * 64 + r] = h;
    st_c[bid * 64 + r] = c;
    st_s[bid * 64 + r] = hsum;
}

// ---------------------------------------------------------------------------
// Head: out[b] = dot(hsum_fwd, fcw[0:64]) + dot(hsum_bwd, fcw[64:128]) over T,
// divided by T, plus bias.
// ---------------------------------------------------------------------------
__global__ __launch_bounds__(64) void fc_head(
    const float* __restrict__ state,
    const float* __restrict__ fcw, const float* __restrict__ fcb,
    float* __restrict__ out)
{
    const int b = blockIdx.x;
    const int l = threadIdx.x;
    const float* hs = state + 2 * 1024 * 64;
    float v = hs[(b * 2) * 64 + l] * fcw[l] + hs[(b * 2 + 1) * 64 + l] * fcw[64 + l];
#pragma unroll
    for (int o = 32; o > 0; o >>= 1) v += __shfl_down(v, o);
    if (l == 0) out[b] = v * (1.f / (float)TT) + fcb[0];
}

extern "C" void kernel_launch(void* const* d_in, const int* in_sizes, int n_in,
                              void* d_out, int out_size, void* d_ws, size_t ws_size,
                              hipStream_t stream) {
    const float* x       = (const float*)d_in[0];
    const float* Wih_l0f = (const float*)d_in[1];
    const float* Whh_l0f = (const float*)d_in[2];
    const float* b_l0f   = (const float*)d_in[3];
    const float* Wih_l0b = (const float*)d_in[4];
    const float* Whh_l0b = (const float*)d_in[5];
    const float* b_l0b   = (const float*)d_in[6];
    const float* Wih_l1f = (const float*)d_in[7];
    const float* Whh_l1f = (const float*)d_in[8];
    const float* b_l1f   = (const float*)d_in[9];
    const float* Wih_l1b = (const float*)d_in[10];
    const float* Whh_l1b = (const float*)d_in[11];
    const float* b_l1b   = (const float*)d_in[12];
    const float* fcw     = (const float*)d_in[13];
    const float* fcb     = (const float*)d_in[14];

    // Workspace layout (all offsets 256-aligned)
    const size_t o_out0  = 0;                               // [B*T,128] fp16 = 64 MiB
    const size_t o_wb    = o_out0 + (size_t)BB*TT*128*2;    // 67,108,864
    const size_t o_state = o_wb + 2*256*128*2;              // +131,072
    const size_t o_xp    = o_state + 3*1024*64*4;           // +786,432

    __half* out0  = (__half*)((char*)d_ws + o_out0);
    __half* Wb    = (__half*)((char*)d_ws + o_wb);
    float*  state = (float*)((char*)d_ws + o_state);

    // Pick largest chunk length Tc whose xp buffers fit in ws.
    int Tc = 512;
    while (Tc > 32) {
        size_t xpb = (size_t)BB * Tc * 256 * 2;             // per direction
        if (o_xp + 2 * xpb <= ws_size) break;
        Tc >>= 1;
    }
    const size_t xpb = (size_t)BB * Tc * 256 * 2;
    __half* xpF = (__half*)((char*)d_ws + o_xp);
    __half* xpB = (__half*)((char*)d_ws + o_xp + xpb);
    int tcShift = 0; while ((1 << tcShift) < Tc) ++tcShift;
    const int nStages = TT / Tc;

    prep_w<<<256, 256, 0, stream>>>(Wih_l1f, Wih_l1b, Wb);
    lstm_l0<<<BB * 2, 64, 0, stream>>>(x, Wih_l0f, Whh_l0f, b_l0f,
                                       Wih_l0b, Whh_l0b, b_l0b, out0);
    for (int s = 0; s < nStages; ++s) {
        dim3 grid((BB * Tc) / 64, 2);
        xp_gemm<<<grid, 256, 0, stream>>>(out0, Wb, xpF, xpB, s, Tc, tcShift);
        lstm_l1_rec<<<BB * 2, 64, 0, stream>>>(xpF, xpB, Whh_l1f, b_l1f,
                                               Whh_l1b, b_l1b, state, Tc, s == 0);
    }
    fc_head<<<BB, 64, 0, stream>>>(state, fcw, fcb, (float*)d_out);
}

// Round 3
// 1294.444 us; speedup vs baseline: 1.5262x; 1.3309x over previous
//
#include <hip/hip_runtime.h>
#include <hip/hip_fp16.h>

#define H  64
#define TT 512
#define BB 512

typedef _Float16 half8 __attribute__((ext_vector_type(8)));
typedef float    f32x4 __attribute__((ext_vector_type(4)));

__device__ __forceinline__ float sigm(float x) { return 1.f / (1.f + __expf(-x)); }
__device__ __forceinline__ float tanh_fast(float x) { return 1.f - 2.f / (__expf(2.f * x) + 1.f); }

// ---------------------------------------------------------------------------
// Prep: convert layer-1 Wih to fp16, permuted so output col = unit*4 + gate.
// out[dir][unit*4+gate][k] = (half) Wih_dir[gate*64+unit][k]
// ---------------------------------------------------------------------------
__global__ __launch_bounds__(256) void prep_w(const float* __restrict__ wf,
                                              const float* __restrict__ wb,
                                              __half* __restrict__ out) {
    int i = blockIdx.x * 256 + threadIdx.x;      // 0 .. 65535
    int dir  = i >> 15;
    int rem  = i & 32767;
    int rowp = rem >> 7;                          // permuted row 0..255
    int k    = rem & 127;
    int unit = rowp >> 2;
    int gate = rowp & 3;
    const float* src = dir ? wb : wf;
    out[i] = __float2half(src[(gate * 64 + unit) * 128 + k]);
}

// ---------------------------------------------------------------------------
// Layer 0: 128 threads (2 waves) per (batch, dir) chain. Thread (u = r&63,
// pair = r>>6) owns gates (2*pair, 2*pair+1) of unit u: 128 weight VGPRs.
// Wave 0 owns (i,f) and does the c/h update locally; wave 1 publishes (g,o)
// through LDS. h double-buffered in LDS -> 2 barriers/step. No spills.
// Writes h as fp16 into out0 [B*T, 128] (cols 0-63 fwd, 64-127 bwd).
// ---------------------------------------------------------------------------
__global__ __launch_bounds__(128, 2) void lstm_l0(
    const float* __restrict__ x,
    const float* __restrict__ WihF, const float* __restrict__ WhhF, const float* __restrict__ bF,
    const float* __restrict__ WihB, const float* __restrict__ WhhB, const float* __restrict__ bB,
    __half* __restrict__ out0)
{
    const int bid  = blockIdx.x;
    const int b    = bid >> 1;
    const int dir  = bid & 1;
    const int r    = threadIdx.x;
    const int u    = r & 63;
    const int pair = r >> 6;          // wave-uniform

    const float* Wih  = dir ? WihB : WihF;
    const float* Whh  = dir ? WhhB : WhhF;
    const float* bias = dir ? bB   : bF;

    const int g0 = 2 * pair, g1 = 2 * pair + 1;
    float4 wx0 = ((const float4*)Wih)[g0 * 64 + u];
    float4 wx1 = ((const float4*)Wih)[g1 * 64 + u];
    const float bv0 = bias[g0 * 64 + u];
    const float bv1 = bias[g1 * 64 + u];

    float4 wh0[16], wh1[16];
#pragma unroll
    for (int j = 0; j < 16; ++j) {
        wh0[j] = ((const float4*)(Whh + (g0 * 64 + u) * H))[j];
        wh1[j] = ((const float4*)(Whh + (g1 * 64 + u) * H))[j];
    }

    __shared__ __align__(16) float h_sh[2][H];
    __shared__ __align__(16) float gate_sh[2 * H];   // g, o from wave 1
    float c = 0.f, h = 0.f;
    if (pair == 0) h_sh[0][u] = 0.f;
    __syncthreads();

    const float4* x4 = (const float4*)x + (size_t)b * TT;
    const int dt = dir ? -1 : 1;
    int t = dir ? (TT - 1) : 0;
    float4 xt = x4[t];
    int p = 0;

    for (int s = 0; s < TT; ++s) {
        float4 xn = x4[(s + 1 < TT) ? (t + dt) : t];

        float a0 = bv0 + wx0.x*xt.x + wx0.y*xt.y + wx0.z*xt.z + wx0.w*xt.w;
        float a1 = bv1 + wx1.x*xt.x + wx1.y*xt.y + wx1.z*xt.z + wx1.w*xt.w;

        const float4* h4 = (const float4*)h_sh[p];
#pragma unroll
        for (int j = 0; j < 16; ++j) {
            float4 hv = h4[j];
            a0 += wh0[j].x*hv.x + wh0[j].y*hv.y + wh0[j].z*hv.z + wh0[j].w*hv.w;
            a1 += wh1[j].x*hv.x + wh1[j].y*hv.y + wh1[j].z*hv.z + wh1[j].w*hv.w;
        }
        // pair 0: i = sigm(a0), f = sigm(a1).  pair 1: g = tanh(a0), o = sigm(a1).
        float v0 = pair ? tanh_fast(a0) : sigm(a0);
        float v1 = sigm(a1);
        if (pair) { gate_sh[u] = v0; gate_sh[64 + u] = v1; }
        __syncthreads();
        if (!pair) {
            float gv = gate_sh[u], ov = gate_sh[64 + u];
            c = v1 * c + v0 * gv;
            h = ov * tanh_fast(c);
            h_sh[p ^ 1][u] = h;
            out0[(size_t)(b * TT + t) * 128 + dir * 64 + u] = __float2half(h);
        }
        __syncthreads();
        p ^= 1; xt = xn; t += dt;
    }
}

// ---------------------------------------------------------------------------
// xp GEMM: xp[dir][m][n] = sum_k A[m'][k] * Wb[dir][n][k]  (fp16 in, fp32 acc,
// fp16 out), n = unit*4+gate. Block = 256 thr = 4 waves; block tile 64m x 256n.
// ---------------------------------------------------------------------------
__global__ __launch_bounds__(256) void xp_gemm(
    const __half* __restrict__ A,      // [B*T, 128]
    const __half* __restrict__ Wb,     // [2][256][128] permuted fp16
    __half* __restrict__ xpF, __half* __restrict__ xpB,
    int s, int Tc, int tcShift)
{
    const int dir  = blockIdx.y;
    const int mb   = blockIdx.x;
    const int w    = threadIdx.x >> 6;
    const int lane = threadIdx.x & 63;
    const int quad = lane >> 4;
    const int l16  = lane & 15;

    const int mbase = mb * 64 + w * 16;
    const int m     = mbase + l16;                 // chunk-local row for A-frag
    const int bb    = m >> tcShift;
    const int u     = m & (Tc - 1);
    const int t     = dir ? (TT - 1 - s * Tc - u) : (s * Tc + u);

    const __half* arow = A + (size_t)(bb * TT + t) * 128;
    const __half* wdir = Wb + (size_t)dir * 256 * 128;

    f32x4 acc[16];
#pragma unroll
    for (int nt = 0; nt < 16; ++nt) acc[nt] = (f32x4){0.f, 0.f, 0.f, 0.f};

#pragma unroll
    for (int kk = 0; kk < 4; ++kk) {
        half8 a = *(const half8*)(arow + kk * 32 + quad * 8);
#pragma unroll
        for (int nt = 0; nt < 16; ++nt) {
            half8 bf = *(const half8*)(wdir + (size_t)(nt * 16 + l16) * 128 + kk * 32 + quad * 8);
            acc[nt] = __builtin_amdgcn_mfma_f32_16x16x32_f16(a, bf, acc[nt], 0, 0, 0);
        }
    }

    __shared__ __align__(16) __half c_sh[4][16][264];
#pragma unroll
    for (int nt = 0; nt < 16; ++nt)
#pragma unroll
        for (int i = 0; i < 4; ++i)
            c_sh[w][quad * 4 + i][nt * 16 + l16] = __float2half(acc[nt][i]);
    __syncthreads();

    __half* dst = (dir ? xpB : xpF) + (size_t)mbase * 256;
#pragma unroll
    for (int rd = 0; rd < 8; ++rd) {
        int ci  = rd * 64 + lane;
        int row = ci >> 5;
        int off = ci & 31;
        float4 v = *(const float4*)((const char*)&c_sh[w][row][0] + off * 16);
        *(float4*)((char*)dst + (size_t)row * 512 + off * 16) = v;
    }
}

// ---------------------------------------------------------------------------
// Layer 1 recurrent: same 128-thr/chain structure as lstm_l0; input term is
// one aligned __half2 from xp (cols 4u+2*pair, +1), prefetched one step.
// ---------------------------------------------------------------------------
__global__ __launch_bounds__(128, 2) void lstm_l1_rec(
    const __half* __restrict__ xpF, const __half* __restrict__ xpB,
    const float* __restrict__ WhhF, const float* __restrict__ bF,
    const float* __restrict__ WhhB, const float* __restrict__ bB,
    float* __restrict__ state,        // [3][1024][64] : h, c, hsum
    int Tc, int first)
{
    const int bid  = blockIdx.x;
    const int b    = bid >> 1;
    const int dir  = bid & 1;
    const int r    = threadIdx.x;
    const int u    = r & 63;
    const int pair = r >> 6;

    const float* Whh  = dir ? WhhB : WhhF;
    const float* bias = dir ? bB   : bF;

    const int g0 = 2 * pair, g1 = 2 * pair + 1;
    const float bv0 = bias[g0 * 64 + u];
    const float bv1 = bias[g1 * 64 + u];

    float4 wh0[16], wh1[16];
#pragma unroll
    for (int j = 0; j < 16; ++j) {
        wh0[j] = ((const float4*)(Whh + (g0 * 64 + u) * H))[j];
        wh1[j] = ((const float4*)(Whh + (g1 * 64 + u) * H))[j];
    }

    float* st_h = state;
    float* st_c = state + 1024 * 64;
    float* st_s = state + 2 * 1024 * 64;

    float h = 0.f, c = 0.f, hsum = 0.f;
    if (!first && pair == 0) {
        h = st_h[bid * 64 + u]; c = st_c[bid * 64 + u]; hsum = st_s[bid * 64 + u];
    }

    __shared__ __align__(16) float h_sh[2][H];
    __shared__ __align__(16) float gate_sh[2 * H];
    if (pair == 0) h_sh[0][u] = h;
    __syncthreads();

    const __half* xp = (dir ? xpB : xpF) + (size_t)b * Tc * 256 + 4 * u + 2 * pair;
    __half2 xv = *(const __half2*)xp;
    int p = 0;

    for (int uu = 0; uu < Tc; ++uu) {
        int un = (uu + 1 < Tc) ? (uu + 1) : uu;
        __half2 xn = *(const __half2*)(xp + (size_t)un * 256);

        float a0 = bv0 + __low2float(xv);
        float a1 = bv1 + __high2float(xv);

        const float4* h4 = (const float4*)h_sh[p];
#pragma unroll
        for (int j = 0; j < 16; ++j) {
            float4 hv = h4[j];
            a0 += wh0[j].x*hv.x + wh0[j].y*hv.y + wh0[j].z*hv.z + wh0[j].w*hv.w;
            a1 += wh1[j].x*hv.x + wh1[j].y*hv.y + wh1[j].z*hv.z + wh1[j].w*hv.w;
        }
        float v0 = pair ? tanh_fast(a0) : sigm(a0);
        float v1 = sigm(a1);
        if (pair) { gate_sh[u] = v0; gate_sh[64 + u] = v1; }
        __syncthreads();
        if (!pair) {
            float gv = gate_sh[u], ov = gate_sh[64 + u];
            c = v1 * c + v0 * gv;
            h = ov * tanh_fast(c);
            hsum += h;
            h_sh[p ^ 1][u] = h;
        }
        __syncthreads();
        p ^= 1; xv = xn;
    }

    if (pair == 0) {
        st_h[bid * 64 + u] = h;
        st_c[bid * 64 + u] = c;
        st_s[bid * 64 + u] = hsum;
    }
}

// ---------------------------------------------------------------------------
// Head: out[b] = (dot(hsum_f, fcw[0:64]) + dot(hsum_b, fcw[64:128])) / T + fcb
// ---------------------------------------------------------------------------
__global__ __launch_bounds__(64) void fc_head(
    const float* __restrict__ state,
    const float* __restrict__ fcw, const float* __restrict__ fcb,
    float* __restrict__ out)
{
    const int b = blockIdx.x;
    const int l = threadIdx.x;
    const float* hs = state + 2 * 1024 * 64;
    float v = hs[(b * 2) * 64 + l] * fcw[l] + hs[(b * 2 + 1) * 64 + l] * fcw[64 + l];
#pragma unroll
    for (int o = 32; o > 0; o >>= 1) v += __shfl_down(v, o);
    if (l == 0) out[b] = v * (1.f / (float)TT) + fcb[0];
}

extern "C" void kernel_launch(void* const* d_in, const int* in_sizes, int n_in,
                              void* d_out, int out_size, void* d_ws, size_t ws_size,
                              hipStream_t stream) {
    const float* x       = (const float*)d_in[0];
    const float* Wih_l0f = (const float*)d_in[1];
    const float* Whh_l0f = (const float*)d_in[2];
    const float* b_l0f   = (const float*)d_in[3];
    const float* Wih_l0b = (const float*)d_in[4];
    const float* Whh_l0b = (const float*)d_in[5];
    const float* b_l0b   = (const float*)d_in[6];
    const float* Wih_l1f = (const float*)d_in[7];
    const float* Whh_l1f = (const float*)d_in[8];
    const float* b_l1f   = (const float*)d_in[9];
    const float* Wih_l1b = (const float*)d_in[10];
    const float* Whh_l1b = (const float*)d_in[11];
    const float* b_l1b   = (const float*)d_in[12];
    const float* fcw     = (const float*)d_in[13];
    const float* fcb     = (const float*)d_in[14];

    const size_t o_out0  = 0;                               // [B*T,128] fp16 = 64 MiB
    const size_t o_wb    = o_out0 + (size_t)BB*TT*128*2;
    const size_t o_state = o_wb + 2*256*128*2;
    const size_t o_xp    = o_state + 3*1024*64*4;

    __half* out0  = (__half*)((char*)d_ws + o_out0);
    __half* Wb    = (__half*)((char*)d_ws + o_wb);
    float*  state = (float*)((char*)d_ws + o_state);

    int Tc = 512;
    while (Tc > 32) {
        size_t xpb = (size_t)BB * Tc * 256 * 2;
        if (o_xp + 2 * xpb <= ws_size) break;
        Tc >>= 1;
    }
    const size_t xpb = (size_t)BB * Tc * 256 * 2;
    __half* xpF = (__half*)((char*)d_ws + o_xp);
    __half* xpB = (__half*)((char*)d_ws + o_xp + xpb);
    int tcShift = 0; while ((1 << tcShift) < Tc) ++tcShift;
    const int nStages = TT / Tc;

    prep_w<<<256, 256, 0, stream>>>(Wih_l1f, Wih_l1b, Wb);
    lstm_l0<<<BB * 2, 128, 0, stream>>>(x, Wih_l0f, Whh_l0f, b_l0f,
                                        Wih_l0b, Whh_l0b, b_l0b, out0);
    for (int s = 0; s < nStages; ++s) {
        dim3 grid((BB * Tc) / 64, 2);
        xp_gemm<<<grid, 256, 0, stream>>>(out0, Wb, xpF, xpB, s, Tc, tcShift);
        lstm_l1_rec<<<BB * 2, 128, 0, stream>>>(xpF, xpB, Whh_l1f, b_l1f,
                                                Whh_l1b, b_l1b, state, Tc, s == 0);
    }
    fc_head<<<BB, 64, 0, stream>>>(state, fcw, fcb, (float*)d_out);
}

// Round 4
// 769.574 us; speedup vs baseline: 2.5672x; 1.6820x over previous
//
#include <hip/hip_runtime.h>

#define H  64
#define TT 512
#define BB 512

typedef _Float16 half8 __attribute__((ext_vector_type(8)));
typedef float    f32x4 __attribute__((ext_vector_type(4)));

__device__ __forceinline__ float frcp(float x) { return __builtin_amdgcn_rcpf(x); }
__device__ __forceinline__ float sigm(float x) { return frcp(1.f + __expf(-x)); }
__device__ __forceinline__ float tanh_fast(float x) { return 1.f - 2.f * frcp(__expf(2.f * x) + 1.f); }

// ---------------------------------------------------------------------------
// xpad: [B*T][32] fp16, cols 0..3 = x (fp32->fp16), cols 4..31 = 0.
// One thread per 16B chunk -> fully coalesced.
// ---------------------------------------------------------------------------
__global__ __launch_bounds__(256) void xpad_prep(const float* __restrict__ x,
                                                 _Float16* __restrict__ xpad) {
    int gid = blockIdx.x * 256 + threadIdx.x;     // B*T*4 chunks of 8 halves
    int row = gid >> 2, q = gid & 3;
    half8 v = {0,0,0,0,0,0,0,0};
    if (q == 0) {
        float4 xv = ((const float4*)x)[row];
        v[0] = (_Float16)xv.x; v[1] = (_Float16)xv.y;
        v[2] = (_Float16)xv.z; v[3] = (_Float16)xv.w;
    }
    *(half8*)(xpad + (size_t)row * 32 + q * 8) = v;
}

// ---------------------------------------------------------------------------
// MFMA LSTM layer 0. Block = 256 thr = 4 waves, 16 chains (same dir).
// Wave w owns units [w*16, w*16+16) x 4 gates = 4 accumulators; M rows = chains.
// A = [h fp16 (LDS, swizzled) | xpad_t (global, prefetched)], K = 96.
// B (Whh|Wih0 fp16) lives in VGPRs. State c fp32 in regs. 1 barrier/step.
// ---------------------------------------------------------------------------
__global__ __launch_bounds__(256) void lstm_l0(
    const _Float16* __restrict__ xpad,
    const float* __restrict__ WihF, const float* __restrict__ WhhF, const float* __restrict__ bF,
    const float* __restrict__ WihB, const float* __restrict__ WhhB, const float* __restrict__ bB,
    _Float16* __restrict__ out0)
{
    const int dir = blockIdx.x & 1;
    const int b0  = (blockIdx.x >> 1) * 16;
    const int tid = threadIdx.x;
    const int w = tid >> 6, l = tid & 63, m = l & 15, q = l >> 4;

    const float* Wih = dir ? WihB : WihF;
    const float* Whh = dir ? WhhB : WhhF;
    const float* bia = dir ? bB   : bF;

    half8 Bh[4][2], Bx[4];
    float bv[4];
#pragma unroll
    for (int g = 0; g < 4; ++g) {
        const int n = g * 64 + w * 16 + m;        // gate-major row (PyTorch order)
        bv[g] = bia[n];
#pragma unroll
        for (int s = 0; s < 2; ++s) {
            const float* src = Whh + n * 64 + s * 32 + q * 8;
            half8 tmp;
#pragma unroll
            for (int j = 0; j < 8; ++j) tmp[j] = (_Float16)src[j];
            Bh[g][s] = tmp;
        }
        half8 tx;
#pragma unroll
        for (int j = 0; j < 8; ++j) {
            int k = q * 8 + j;
            tx[j] = (k < 4) ? (_Float16)Wih[n * 4 + k] : (_Float16)0.f;
        }
        Bx[g] = tx;
    }

    __shared__ _Float16 hbuf[2][1024];            // [2][16 chains][64 units], 16B-XOR swizzle
    ((unsigned long long*)hbuf)[tid] = 0ULL;      // zero hbuf[0] (2 KB)
    __syncthreads();

    float c[4] = {0.f, 0.f, 0.f, 0.f};
    const int dt = dir ? -1 : 1;
    int t = dir ? TT - 1 : 0;
    const _Float16* xrow = xpad + (size_t)(b0 + m) * TT * 32 + q * 8;
    half8 ax = *(const half8*)(xrow + t * 32);
    int p = 0;
    const int swz = (m & 7) * 16;

    for (int s = 0; s < TT; ++s) {
        const char* hb = (const char*)hbuf[p];
        half8 ah0 = *(const half8*)(hb + m * 128 + ((     q * 16 + swz) & 127));
        half8 ah1 = *(const half8*)(hb + m * 128 + ((64 + q * 16 + swz) & 127));
        int tn = t + ((s + 1 < TT) ? dt : 0);
        half8 axn = *(const half8*)(xrow + tn * 32);

        f32x4 acc[4];
#pragma unroll
        for (int g = 0; g < 4; ++g) {
            f32x4 a = {bv[g], bv[g], bv[g], bv[g]};
            a = __builtin_amdgcn_mfma_f32_16x16x32_f16(ah0, Bh[g][0], a, 0, 0, 0);
            a = __builtin_amdgcn_mfma_f32_16x16x32_f16(ah1, Bh[g][1], a, 0, 0, 0);
            acc[g] = __builtin_amdgcn_mfma_f32_16x16x32_f16(ax, Bx[g], a, 0, 0, 0);
        }

        char* hbn = (char*)hbuf[p ^ 1];
#pragma unroll
        for (int i = 0; i < 4; ++i) {             // cell (chain=q*4+i, unit=w*16+m)
            float e_i = sigm(acc[0][i]), e_f = sigm(acc[1][i]);
            float e_g = tanh_fast(acc[2][i]), e_o = sigm(acc[3][i]);
            c[i] = e_f * c[i] + e_i * e_g;
            float hh = e_o * tanh_fast(c[i]);
            const int ch = q * 4 + i;
            out0[((size_t)(b0 + ch) * TT + t) * 128 + dir * 64 + w * 16 + m] = (_Float16)hh;
            *(_Float16*)(hbn + ch * 128 + (((w * 16 + m) * 2 + (ch & 7) * 16) & 127)) = (_Float16)hh;
        }
        __syncthreads();
        p ^= 1; t += dt; ax = axn;
    }
}

// ---------------------------------------------------------------------------
// MFMA LSTM layer 1: same structure, K = 64 (h) + 128 (x from out0) = 192.
// Accumulates hsum (fp32) for the mean-pool; writes pooled[B][128].
// ---------------------------------------------------------------------------
__global__ __launch_bounds__(256) void lstm_l1(
    const _Float16* __restrict__ out0,
    const float* __restrict__ WihF, const float* __restrict__ WhhF, const float* __restrict__ bF,
    const float* __restrict__ WihB, const float* __restrict__ WhhB, const float* __restrict__ bB,
    float* __restrict__ pooled)
{
    const int dir = blockIdx.x & 1;
    const int b0  = (blockIdx.x >> 1) * 16;
    const int tid = threadIdx.x;
    const int w = tid >> 6, l = tid & 63, m = l & 15, q = l >> 4;

    const float* Wih = dir ? WihB : WihF;
    const float* Whh = dir ? WhhB : WhhF;
    const float* bia = dir ? bB   : bF;

    half8 Bf[4][6];
    float bv[4];
#pragma unroll
    for (int g = 0; g < 4; ++g) {
        const int n = g * 64 + w * 16 + m;
        bv[g] = bia[n];
#pragma unroll
        for (int s = 0; s < 6; ++s) {
            const float* src = (s < 2) ? (Whh + n * 64 + s * 32 + q * 8)
                                       : (Wih + n * 128 + (s - 2) * 32 + q * 8);
            half8 tmp;
#pragma unroll
            for (int j = 0; j < 8; ++j) tmp[j] = (_Float16)src[j];
            Bf[g][s] = tmp;
        }
    }

    __shared__ _Float16 hbuf[2][1024];
    ((unsigned long long*)hbuf)[tid] = 0ULL;
    __syncthreads();

    float c[4]  = {0.f, 0.f, 0.f, 0.f};
    float hs[4] = {0.f, 0.f, 0.f, 0.f};
    const int dt = dir ? -1 : 1;
    int t = dir ? TT - 1 : 0;
    const _Float16* xrow = out0 + (size_t)(b0 + m) * TT * 128 + q * 8;

    half8 ax[4];
#pragma unroll
    for (int s4 = 0; s4 < 4; ++s4) ax[s4] = *(const half8*)(xrow + t * 128 + s4 * 32);
    int p = 0;
    const int swz = (m & 7) * 16;

    for (int s = 0; s < TT; ++s) {
        const char* hb = (const char*)hbuf[p];
        half8 ah0 = *(const half8*)(hb + m * 128 + ((     q * 16 + swz) & 127));
        half8 ah1 = *(const half8*)(hb + m * 128 + ((64 + q * 16 + swz) & 127));
        int tn = t + ((s + 1 < TT) ? dt : 0);
        half8 axn[4];
#pragma unroll
        for (int s4 = 0; s4 < 4; ++s4) axn[s4] = *(const half8*)(xrow + tn * 128 + s4 * 32);

        f32x4 acc[4];
#pragma unroll
        for (int g = 0; g < 4; ++g) {
            f32x4 a = {bv[g], bv[g], bv[g], bv[g]};
            a = __builtin_amdgcn_mfma_f32_16x16x32_f16(ah0,   Bf[g][0], a, 0, 0, 0);
            a = __builtin_amdgcn_mfma_f32_16x16x32_f16(ah1,   Bf[g][1], a, 0, 0, 0);
            a = __builtin_amdgcn_mfma_f32_16x16x32_f16(ax[0], Bf[g][2], a, 0, 0, 0);
            a = __builtin_amdgcn_mfma_f32_16x16x32_f16(ax[1], Bf[g][3], a, 0, 0, 0);
            a = __builtin_amdgcn_mfma_f32_16x16x32_f16(ax[2], Bf[g][4], a, 0, 0, 0);
            acc[g] = __builtin_amdgcn_mfma_f32_16x16x32_f16(ax[3], Bf[g][5], a, 0, 0, 0);
        }

        char* hbn = (char*)hbuf[p ^ 1];
#pragma unroll
        for (int i = 0; i < 4; ++i) {
            float e_i = sigm(acc[0][i]), e_f = sigm(acc[1][i]);
            float e_g = tanh_fast(acc[2][i]), e_o = sigm(acc[3][i]);
            c[i] = e_f * c[i] + e_i * e_g;
            float hh = e_o * tanh_fast(c[i]);
            hs[i] += hh;
            const int ch = q * 4 + i;
            *(_Float16*)(hbn + ch * 128 + (((w * 16 + m) * 2 + (ch & 7) * 16) & 127)) = (_Float16)hh;
        }
        __syncthreads();
        p ^= 1; t += dt;
#pragma unroll
        for (int s4 = 0; s4 < 4; ++s4) ax[s4] = axn[s4];
    }

#pragma unroll
    for (int i = 0; i < 4; ++i)
        pooled[(size_t)(b0 + q * 4 + i) * 128 + dir * 64 + w * 16 + m] = hs[i];
}

// ---------------------------------------------------------------------------
// Head: out[b] = dot(pooled[b], fcw) / T + fcb
// ---------------------------------------------------------------------------
__global__ __launch_bounds__(64) void fc_head(
    const float* __restrict__ pooled,
    const float* __restrict__ fcw, const float* __restrict__ fcb,
    float* __restrict__ out)
{
    const int b = blockIdx.x;
    const int l = threadIdx.x;
    float v = pooled[b * 128 + l] * fcw[l] + pooled[b * 128 + 64 + l] * fcw[64 + l];
#pragma unroll
    for (int o = 32; o > 0; o >>= 1) v += __shfl_down(v, o);
    if (l == 0) out[b] = v * (1.f / (float)TT) + fcb[0];
}

extern "C" void kernel_launch(void* const* d_in, const int* in_sizes, int n_in,
                              void* d_out, int out_size, void* d_ws, size_t ws_size,
                              hipStream_t stream) {
    const float* x       = (const float*)d_in[0];
    const float* Wih_l0f = (const float*)d_in[1];
    const float* Whh_l0f = (const float*)d_in[2];
    const float* b_l0f   = (const float*)d_in[3];
    const float* Wih_l0b = (const float*)d_in[4];
    const float* Whh_l0b = (const float*)d_in[5];
    const float* b_l0b   = (const float*)d_in[6];
    const float* Wih_l1f = (const float*)d_in[7];
    const float* Whh_l1f = (const float*)d_in[8];
    const float* b_l1f   = (const float*)d_in[9];
    const float* Wih_l1b = (const float*)d_in[10];
    const float* Whh_l1b = (const float*)d_in[11];
    const float* b_l1b   = (const float*)d_in[12];
    const float* fcw     = (const float*)d_in[13];
    const float* fcb     = (const float*)d_in[14];

    // ws: xpad [B*T][32] fp16 (16 MiB) | out0 [B*T][128] fp16 (64 MiB) | pooled [B][128] f32
    const size_t o_xpad   = 0;
    const size_t o_out0   = o_xpad + (size_t)BB * TT * 32 * 2;
    const size_t o_pooled = o_out0 + (size_t)BB * TT * 128 * 2;

    _Float16* xpad   = (_Float16*)((char*)d_ws + o_xpad);
    _Float16* out0   = (_Float16*)((char*)d_ws + o_out0);
    float*    pooled = (float*)((char*)d_ws + o_pooled);

    xpad_prep<<<(BB * TT * 4) / 256, 256, 0, stream>>>(x, xpad);
    lstm_l0<<<(BB / 16) * 2, 256, 0, stream>>>(xpad, Wih_l0f, Whh_l0f, b_l0f,
                                               Wih_l0b, Whh_l0b, b_l0b, out0);
    lstm_l1<<<(BB / 16) * 2, 256, 0, stream>>>(out0, Wih_l1f, Whh_l1f, b_l1f,
                                               Wih_l1b, Whh_l1b, b_l1b, pooled);
    fc_head<<<BB, 64, 0, stream>>>(pooled, fcw, fcb, (float*)d_out);
}